// Round 5
// baseline (471.728 us; speedup 1.0000x reference)
//
#include <hip/hip_runtime.h>
#include <hip/hip_bf16.h>
#include <math.h>

// GCN 2-layer: h = Ddst^-1/2 A (Dsrc^-1/2 x) W + b, relu between.
// R5 (= R4 retry): degree counting via LDS-privatized range-partitioned
// histogram (R3: count_kernel 64us, device-atomic-bound, 32B/atomic fabric
// writeback). RSZ cut to 8192 (32KB LDS) to stay clear of the 64KB static
// LDS limit suspected in the R4 container failure.
// CSR SpMM (R2) + bf16 MFMA GEMM1 (R3) retained.

#define F_IN  256
#define F_HID 128
#define F_CLS 40

#define RSZ 8192    // nodes per histogram range (32KB LDS of uint counters)
#define NSL 16      // edge slices

typedef __bf16 bf16_t;
typedef bf16_t bf16x8 __attribute__((ext_vector_type(8)));
typedef float floatx4 __attribute__((ext_vector_type(4)));

static __device__ __forceinline__ unsigned short f2b(float f) {
    __hip_bfloat16 h = __float2bfloat16(f);   // RNE
    return __builtin_bit_cast(unsigned short, h);
}
static __device__ __forceinline__ float b2f(unsigned short u) {
    return __uint_as_float((unsigned)u << 16);
}

// ---- histogram partials: block (r, sl, y) counts keys-in-range from slice --
__global__ __launch_bounds__(256) void hist_kernel(
    const int* __restrict__ src, const int* __restrict__ dst,
    unsigned* __restrict__ partial_s, unsigned* __restrict__ partial_d, int E)
{
    __shared__ unsigned h[RSZ];
    const int t = threadIdx.x;
    const int r  = blockIdx.x / NSL;
    const int sl = blockIdx.x % NSL;
    const int lo = r * RSZ;
    const int* __restrict__ keys = blockIdx.y ? dst : src;
    unsigned* __restrict__ part = blockIdx.y ? partial_d : partial_s;

    for (int i = t; i < RSZ; i += 256) h[i] = 0;
    __syncthreads();

    const int slice = (E + NSL - 1) / NSL;
    const int e0 = sl * slice;
    const int e1 = min(E, e0 + slice);
    for (int e = e0 + t; e < e1; e += 256) {
        unsigned k = (unsigned)(keys[e] - lo);
        if (k < RSZ) atomicAdd(&h[k], 1u);
    }
    __syncthreads();

    unsigned* dst_p = part + (size_t)blockIdx.x * RSZ;
    for (int i = t; i < RSZ; i += 256) dst_p[i] = h[i];
}

// ---- reduce partials -> cnt_dst + norms ------------------------------------
__global__ __launch_bounds__(256) void degnorm_kernel(
    const unsigned* __restrict__ partial_s, const unsigned* __restrict__ partial_d,
    int* __restrict__ cnt_dst, float* __restrict__ norm_src,
    float* __restrict__ norm_dst, int N)
{
    int i = blockIdx.x * 256 + threadIdx.x;
    if (i >= N) return;
    int r = i / RSZ;
    int off = i & (RSZ - 1);
    const unsigned* ps = partial_s + (size_t)r * NSL * RSZ + off;
    const unsigned* pd = partial_d + (size_t)r * NSL * RSZ + off;
    unsigned ss = 0, sd = 0;
    #pragma unroll
    for (int sl = 0; sl < NSL; ++sl) {
        ss += ps[(size_t)sl * RSZ];
        sd += pd[(size_t)sl * RSZ];
    }
    cnt_dst[i] = (int)sd;
    norm_src[i] = ss ? 1.0f / sqrtf((float)ss) : 0.0f;
    norm_dst[i] = sd ? 1.0f / sqrtf((float)sd) : 0.0f;
}

// ---- hierarchical exclusive scan over cnt_dst (1024 elems / block) ---------
__global__ __launch_bounds__(256) void scan1_kernel(const int* __restrict__ cnt,
                                                    int* __restrict__ row_off,
                                                    int* __restrict__ blk_sums, int N) {
    __shared__ int s[256];
    const int t = threadIdx.x;
    const int base = blockIdx.x * 1024 + t * 4;
    int v0 = (base + 0 < N) ? cnt[base + 0] : 0;
    int v1 = (base + 1 < N) ? cnt[base + 1] : 0;
    int v2 = (base + 2 < N) ? cnt[base + 2] : 0;
    int v3 = (base + 3 < N) ? cnt[base + 3] : 0;
    int local = v0 + v1 + v2 + v3;
    s[t] = local;
    __syncthreads();
    for (int off = 1; off < 256; off <<= 1) {
        int x = (t >= off) ? s[t - off] : 0;
        __syncthreads();
        s[t] += x;
        __syncthreads();
    }
    int excl = s[t] - local;
    if (t == 255) blk_sums[blockIdx.x] = s[t];
    if (base + 0 < N) row_off[base + 0] = excl;
    if (base + 1 < N) row_off[base + 1] = excl + v0;
    if (base + 2 < N) row_off[base + 2] = excl + v0 + v1;
    if (base + 3 < N) row_off[base + 3] = excl + v0 + v1 + v2;
}

__global__ __launch_bounds__(256) void scan2_kernel(int* __restrict__ blk_sums, int B) {
    __shared__ int s[256];
    const int t = threadIdx.x;
    int local = (t < B) ? blk_sums[t] : 0;
    s[t] = local;
    __syncthreads();
    for (int off = 1; off < 256; off <<= 1) {
        int x = (t >= off) ? s[t - off] : 0;
        __syncthreads();
        s[t] += x;
        __syncthreads();
    }
    if (t < B) blk_sums[t] = s[t] - local;   // exclusive
}

__global__ __launch_bounds__(256) void scan3_kernel(int* __restrict__ row_off,
                                                    int* __restrict__ cursor,
                                                    const int* __restrict__ blk_sums,
                                                    int N, int E) {
    const int t = threadIdx.x;
    const int base = blockIdx.x * 1024 + t * 4;
    const int add = blk_sums[blockIdx.x];
    #pragma unroll
    for (int i = 0; i < 4; ++i) {
        int idx = base + i;
        if (idx < N) {
            int v = row_off[idx] + add;
            row_off[idx] = v;
            cursor[idx] = v;
        }
    }
    if (blockIdx.x == 0 && t == 0) row_off[N] = E;
}

// ---- scatter edges into CSR (grouped by dst) -------------------------------
__global__ void scatter_kernel(const int* __restrict__ src, const int* __restrict__ dst,
                               int* __restrict__ cursor, int* __restrict__ csr_src, int E) {
    int e = blockIdx.x * blockDim.x + threadIdx.x;
    if (e < E) {
        int pos = atomicAdd(&cursor[dst[e]], 1);
        csr_src[pos] = src[e];
    }
}

// ---- pack W1 [256][128] fp32 -> W1t [128][256] bf16 (n-major, k contig) ----
__global__ __launch_bounds__(256) void pack_w1t_kernel(const float* __restrict__ W1,
                                                       __hip_bfloat16* __restrict__ W1t) {
    int idx = blockIdx.x * 256 + threadIdx.x;     // 32768 total
    int n = idx >> 8;
    int k = idx & 255;
    W1t[idx] = __float2bfloat16(W1[(size_t)k * F_HID + n]);
}

// ---- GEMM1 (MFMA): h1b[N,128] = bf16( (X*norm_src)bf16 @ W1bf16 ) ----------
__global__ __launch_bounds__(256) void gemm1_mfma_kernel(
    const float* __restrict__ X, const __hip_bfloat16* __restrict__ W1t,
    const float* __restrict__ norm_src, __hip_bfloat16* __restrict__ h1b, int N)
{
    __shared__ __hip_bfloat16 As[64][72];
    __shared__ __hip_bfloat16 Bs[128][72];
    const int t = threadIdx.x;
    const int node0 = blockIdx.x * 64;
    const int lane = t & 63;
    const int w = t >> 6;
    const int l15 = lane & 15;
    const int quad = lane >> 4;

    floatx4 acc[8] = {};

    for (int k0 = 0; k0 < F_IN; k0 += 64) {
        #pragma unroll
        for (int i = 0; i < 4; ++i) {
            int f = t + 256 * i;
            int r = f >> 4;
            int cseg = (f & 15) << 2;
            int node = node0 + r;
            float4 v = make_float4(0.f, 0.f, 0.f, 0.f);
            float ns = 0.f;
            if (node < N) {
                v = *(const float4*)(X + (size_t)node * F_IN + k0 + cseg);
                ns = norm_src[node];
            }
            ushort4 pk;
            pk.x = f2b(v.x * ns);
            pk.y = f2b(v.y * ns);
            pk.z = f2b(v.z * ns);
            pk.w = f2b(v.w * ns);
            *(ushort4*)&As[r][cseg] = pk;
        }
        #pragma unroll
        for (int i = 0; i < 4; ++i) {
            int f = t + 256 * i;
            int n = f >> 3;
            int seg = (f & 7) << 3;
            *(uint4*)&Bs[n][seg] = *(const uint4*)(W1t + (size_t)n * F_IN + k0 + seg);
        }
        __syncthreads();

        const int arow = w * 16 + l15;
        #pragma unroll
        for (int ks = 0; ks < 2; ++ks) {
            bf16x8 a = *(const bf16x8*)&As[arow][ks * 32 + quad * 8];
            #pragma unroll
            for (int nt = 0; nt < 8; ++nt) {
                bf16x8 b = *(const bf16x8*)&Bs[nt * 16 + l15][ks * 32 + quad * 8];
                acc[nt] = __builtin_amdgcn_mfma_f32_16x16x32_bf16(a, b, acc[nt], 0, 0, 0);
            }
        }
        __syncthreads();
    }

    #pragma unroll
    for (int nt = 0; nt < 8; ++nt) {
        #pragma unroll
        for (int r = 0; r < 4; ++r) {
            int node = node0 + w * 16 + quad * 4 + r;
            if (node < N)
                h1b[(size_t)node * F_HID + nt * 16 + l15] = __float2bfloat16(acc[nt][r]);
        }
    }
}

// ---- SpMM1 (CSR, bf16 gather): agg1[n,:] = sum h1b[csr_src,:] --------------
__global__ __launch_bounds__(256) void spmm1_csr_kernel(
    const __hip_bfloat16* __restrict__ h1b, const int* __restrict__ row_off,
    const int* __restrict__ csr_src, float* __restrict__ agg1, int N)
{
    const int t = threadIdx.x;
    const int node = blockIdx.x * 8 + (t >> 5);
    if (node >= N) return;
    const int c = (t & 31) << 2;
    const int start = row_off[node];
    const int end = row_off[node + 1];
    float4 acc = make_float4(0.f, 0.f, 0.f, 0.f);
    for (int j = start; j < end; ++j) {
        int s = csr_src[j];
        ushort4 u = *(const ushort4*)(h1b + (size_t)s * F_HID + c);
        acc.x += b2f(u.x);
        acc.y += b2f(u.y);
        acc.z += b2f(u.z);
        acc.w += b2f(u.w);
    }
    *(float4*)(agg1 + (size_t)node * F_HID + c) = acc;
}

// ---- GEMM2: h2[N,40] = relu(agg1*norm_dst + b1)*norm_src @ W2[128,40] ------
__global__ __launch_bounds__(320) void gemm2_kernel(
    const float* __restrict__ agg1, const float* __restrict__ W2,
    const float* __restrict__ b1, const float* __restrict__ norm_src,
    const float* __restrict__ norm_dst, float* __restrict__ h2, int N)
{
    __shared__ float As[64][132];
    __shared__ float Ws[128][40];
    const int t = threadIdx.x;
    const int node0 = blockIdx.x * 64;

    #pragma unroll
    for (int i = 0; i < 4; ++i) {
        int f = t + 320 * i;
        int r = f / 10;
        int kk = (f % 10) * 4;
        *(float4*)&Ws[r][kk] = *(const float4*)(W2 + (size_t)r * F_CLS + kk);
    }
    for (int f = t; f < 2048; f += 320) {
        int r = f >> 5;
        int kk = (f & 31) << 2;
        int node = node0 + r;
        float4 v = make_float4(0.f, 0.f, 0.f, 0.f);
        if (node < N) {
            float4 a = *(const float4*)(agg1 + (size_t)node * F_HID + kk);
            float nd = norm_dst[node];
            float ns = norm_src[node];
            float4 bb = *(const float4*)(b1 + kk);
            v.x = fmaxf(fmaf(a.x, nd, bb.x), 0.f) * ns;
            v.y = fmaxf(fmaf(a.y, nd, bb.y), 0.f) * ns;
            v.z = fmaxf(fmaf(a.z, nd, bb.z), 0.f) * ns;
            v.w = fmaxf(fmaf(a.w, nd, bb.w), 0.f) * ns;
        }
        *(float4*)&As[r][kk] = v;
    }
    __syncthreads();

    const int col = t % 40;
    const int rowg = t / 40;
    float acc[8] = {};
    #pragma unroll 8
    for (int k = 0; k < F_HID; ++k) {
        float w = Ws[k][col];
        #pragma unroll
        for (int i = 0; i < 8; ++i)
            acc[i] = fmaf(As[rowg * 8 + i][k], w, acc[i]);
    }
    #pragma unroll
    for (int i = 0; i < 8; ++i) {
        int node = node0 + rowg * 8 + i;
        if (node < N) h2[(size_t)node * F_CLS + col] = acc[i];
    }
}

// ---- SpMM2 (CSR) + epilogue: out[n,:] = (sum h2[src,:])*norm_dst[n] + b2 ---
__global__ __launch_bounds__(256) void spmm2_csr_kernel(
    const float* __restrict__ h2, const int* __restrict__ row_off,
    const int* __restrict__ csr_src, const float* __restrict__ norm_dst,
    const float* __restrict__ b2, float* __restrict__ out, int N)
{
    const int t = threadIdx.x;
    const int node = blockIdx.x * 16 + (t >> 4);
    const int lane = t & 15;
    if (node >= N || lane >= 10) return;
    const int c = lane << 2;
    const int start = row_off[node];
    const int end = row_off[node + 1];
    float4 acc = make_float4(0.f, 0.f, 0.f, 0.f);
    for (int j = start; j < end; ++j) {
        int s = csr_src[j];
        float4 v = *(const float4*)(h2 + (size_t)s * F_CLS + c);
        acc.x += v.x; acc.y += v.y; acc.z += v.z; acc.w += v.w;
    }
    float nd = norm_dst[node];
    float4 bb = *(const float4*)(b2 + c);
    float4 r;
    r.x = fmaf(acc.x, nd, bb.x);
    r.y = fmaf(acc.y, nd, bb.y);
    r.z = fmaf(acc.z, nd, bb.z);
    r.w = fmaf(acc.w, nd, bb.w);
    *(float4*)(out + (size_t)node * F_CLS + c) = r;
}

extern "C" void kernel_launch(void* const* d_in, const int* in_sizes, int n_in,
                              void* d_out, int out_size, void* d_ws, size_t ws_size,
                              hipStream_t stream) {
    const float* X   = (const float*)d_in[0];
    const int*   src = (const int*)d_in[1];
    const int*   dst = (const int*)d_in[2];
    const float* W1  = (const float*)d_in[3];
    const float* b1  = (const float*)d_in[4];
    const float* W2  = (const float*)d_in[5];
    const float* b2  = (const float*)d_in[6];
    float* out = (float*)d_out;

    const int N = in_sizes[0] / F_IN;
    const int E = in_sizes[1];
    const int NB = (N + 1023) / 1024;     // scan blocks (<= 256)
    const int NR = (N + RSZ - 1) / RSZ;   // histogram ranges

    // workspace layout — keep every array 16B-aligned
    char* w = (char*)d_ws;
    int*   cnt_dst  = (int*)w;                      w += (size_t)N * 4;
    int*   row_off  = (int*)w;                      w += (size_t)(N + 4) * 4;
    int*   cursor   = (int*)w;                      w += (size_t)N * 4;
    int*   blk_sums = (int*)w;                      w += 256 * 4;
    int*   csr_src  = (int*)w;                      w += (size_t)E * 4;
    float* norm_src = (float*)w;                    w += (size_t)N * 4;
    float* norm_dst = (float*)w;                    w += (size_t)N * 4;
    float* agg1     = (float*)w;                    w += (size_t)N * F_HID * 4;
    float* h2       = (float*)w;                    w += (size_t)N * F_CLS * 4;
    __hip_bfloat16* W1t = (__hip_bfloat16*)w;       w += (size_t)F_HID * F_IN * 2;
    __hip_bfloat16* h1b = (__hip_bfloat16*)w;       w += (size_t)N * F_HID * 2;

    // histogram partials alias agg1+h2 region (dead until spmm1 writes agg1)
    unsigned* partial_s = (unsigned*)agg1;                        // NR*NSL*RSZ
    unsigned* partial_d = partial_s + (size_t)NR * NSL * RSZ;     // NR*NSL*RSZ

    hist_kernel<<<dim3(NR * NSL, 2), 256, 0, stream>>>(src, dst, partial_s, partial_d, E);
    degnorm_kernel<<<(N + 255) / 256, 256, 0, stream>>>(partial_s, partial_d,
                                                        cnt_dst, norm_src, norm_dst, N);

    scan1_kernel<<<NB, 256, 0, stream>>>(cnt_dst, row_off, blk_sums, N);
    scan2_kernel<<<1, 256, 0, stream>>>(blk_sums, NB);
    scan3_kernel<<<NB, 256, 0, stream>>>(row_off, cursor, blk_sums, N, E);
    scatter_kernel<<<(E + 255) / 256, 256, 0, stream>>>(src, dst, cursor, csr_src, E);

    pack_w1t_kernel<<<(F_HID * F_IN) / 256, 256, 0, stream>>>(W1, W1t);

    gemm1_mfma_kernel<<<(N + 63) / 64, 256, 0, stream>>>(X, W1t, norm_src, h1b, N);

    spmm1_csr_kernel<<<(N + 7) / 8, 256, 0, stream>>>(h1b, row_off, csr_src, agg1, N);

    gemm2_kernel<<<(N + 63) / 64, 320, 0, stream>>>(agg1, W2, b1, norm_src, norm_dst, h2, N);

    spmm2_csr_kernel<<<(N + 15) / 16, 256, 0, stream>>>(h2, row_off, csr_src, norm_dst, b2, out, N);
}

// Round 6
// 402.962 us; speedup vs baseline: 1.1707x; 1.1707x over previous
//
#include <hip/hip_runtime.h>
#include <hip/hip_bf16.h>
#include <math.h>

// GCN 2-layer: h = Ddst^-1/2 A (Dsrc^-1/2 x) W + b, relu between.
// R6: hist_kernel fixed — R5 showed 1130 cyc/edge (un-pipelined load latency,
// 1.6 blocks/CU). Now: 8x batched independent loads + NSL=32 for TLP.
// CSR SpMM (R2) + bf16 MFMA GEMM1 (R3) retained.

#define F_IN  256
#define F_HID 128
#define F_CLS 40

#define RSZ 8192    // nodes per histogram range (32KB LDS of uint counters)
#define NSL 32      // edge slices

typedef __bf16 bf16_t;
typedef bf16_t bf16x8 __attribute__((ext_vector_type(8)));
typedef float floatx4 __attribute__((ext_vector_type(4)));

static __device__ __forceinline__ unsigned short f2b(float f) {
    __hip_bfloat16 h = __float2bfloat16(f);   // RNE
    return __builtin_bit_cast(unsigned short, h);
}
static __device__ __forceinline__ float b2f(unsigned short u) {
    return __uint_as_float((unsigned)u << 16);
}

// ---- histogram partials: block (r, sl, y) counts keys-in-range from slice --
__global__ __launch_bounds__(256) void hist_kernel(
    const int* __restrict__ src, const int* __restrict__ dst,
    unsigned* __restrict__ partial_s, unsigned* __restrict__ partial_d, int E)
{
    __shared__ unsigned h[RSZ];
    const int t = threadIdx.x;
    const int r  = blockIdx.x / NSL;
    const int sl = blockIdx.x % NSL;
    const int lo = r * RSZ;
    const int* __restrict__ keys = blockIdx.y ? dst : src;
    unsigned* __restrict__ part = blockIdx.y ? partial_d : partial_s;

    for (int i = t; i < RSZ; i += 256) h[i] = 0;
    __syncthreads();

    const int slice = (E + NSL - 1) / NSL;
    const int e0 = sl * slice;
    const int e1 = min(E, e0 + slice);

    // 8x batched loads: one vmcnt drain per 8 independent loads
    int e = e0 + t;
    for (; e + 7 * 256 < e1; e += 8 * 256) {
        int k[8];
        #pragma unroll
        for (int i = 0; i < 8; ++i) k[i] = keys[e + i * 256];
        #pragma unroll
        for (int i = 0; i < 8; ++i) {
            unsigned kk = (unsigned)(k[i] - lo);
            if (kk < RSZ) atomicAdd(&h[kk], 1u);
        }
    }
    for (; e < e1; e += 256) {
        unsigned kk = (unsigned)(keys[e] - lo);
        if (kk < RSZ) atomicAdd(&h[kk], 1u);
    }
    __syncthreads();

    unsigned* dst_p = part + (size_t)blockIdx.x * RSZ;
    for (int i = t; i < RSZ; i += 256) dst_p[i] = h[i];
}

// ---- reduce partials -> cnt_dst + norms ------------------------------------
__global__ __launch_bounds__(256) void degnorm_kernel(
    const unsigned* __restrict__ partial_s, const unsigned* __restrict__ partial_d,
    int* __restrict__ cnt_dst, float* __restrict__ norm_src,
    float* __restrict__ norm_dst, int N)
{
    int i = blockIdx.x * 256 + threadIdx.x;
    if (i >= N) return;
    int r = i / RSZ;
    int off = i & (RSZ - 1);
    const unsigned* ps = partial_s + (size_t)r * NSL * RSZ + off;
    const unsigned* pd = partial_d + (size_t)r * NSL * RSZ + off;
    unsigned ss = 0, sd = 0;
    #pragma unroll
    for (int sl = 0; sl < NSL; ++sl) {
        ss += ps[(size_t)sl * RSZ];
        sd += pd[(size_t)sl * RSZ];
    }
    cnt_dst[i] = (int)sd;
    norm_src[i] = ss ? 1.0f / sqrtf((float)ss) : 0.0f;
    norm_dst[i] = sd ? 1.0f / sqrtf((float)sd) : 0.0f;
}

// ---- hierarchical exclusive scan over cnt_dst (1024 elems / block) ---------
__global__ __launch_bounds__(256) void scan1_kernel(const int* __restrict__ cnt,
                                                    int* __restrict__ row_off,
                                                    int* __restrict__ blk_sums, int N) {
    __shared__ int s[256];
    const int t = threadIdx.x;
    const int base = blockIdx.x * 1024 + t * 4;
    int v0 = (base + 0 < N) ? cnt[base + 0] : 0;
    int v1 = (base + 1 < N) ? cnt[base + 1] : 0;
    int v2 = (base + 2 < N) ? cnt[base + 2] : 0;
    int v3 = (base + 3 < N) ? cnt[base + 3] : 0;
    int local = v0 + v1 + v2 + v3;
    s[t] = local;
    __syncthreads();
    for (int off = 1; off < 256; off <<= 1) {
        int x = (t >= off) ? s[t - off] : 0;
        __syncthreads();
        s[t] += x;
        __syncthreads();
    }
    int excl = s[t] - local;
    if (t == 255) blk_sums[blockIdx.x] = s[t];
    if (base + 0 < N) row_off[base + 0] = excl;
    if (base + 1 < N) row_off[base + 1] = excl + v0;
    if (base + 2 < N) row_off[base + 2] = excl + v0 + v1;
    if (base + 3 < N) row_off[base + 3] = excl + v0 + v1 + v2;
}

__global__ __launch_bounds__(256) void scan2_kernel(int* __restrict__ blk_sums, int B) {
    __shared__ int s[256];
    const int t = threadIdx.x;
    int local = (t < B) ? blk_sums[t] : 0;
    s[t] = local;
    __syncthreads();
    for (int off = 1; off < 256; off <<= 1) {
        int x = (t >= off) ? s[t - off] : 0;
        __syncthreads();
        s[t] += x;
        __syncthreads();
    }
    if (t < B) blk_sums[t] = s[t] - local;   // exclusive
}

__global__ __launch_bounds__(256) void scan3_kernel(int* __restrict__ row_off,
                                                    int* __restrict__ cursor,
                                                    const int* __restrict__ blk_sums,
                                                    int N, int E) {
    const int t = threadIdx.x;
    const int base = blockIdx.x * 1024 + t * 4;
    const int add = blk_sums[blockIdx.x];
    #pragma unroll
    for (int i = 0; i < 4; ++i) {
        int idx = base + i;
        if (idx < N) {
            int v = row_off[idx] + add;
            row_off[idx] = v;
            cursor[idx] = v;
        }
    }
    if (blockIdx.x == 0 && t == 0) row_off[N] = E;
}

// ---- scatter edges into CSR (grouped by dst) -------------------------------
__global__ void scatter_kernel(const int* __restrict__ src, const int* __restrict__ dst,
                               int* __restrict__ cursor, int* __restrict__ csr_src, int E) {
    int e = blockIdx.x * blockDim.x + threadIdx.x;
    if (e < E) {
        int pos = atomicAdd(&cursor[dst[e]], 1);
        csr_src[pos] = src[e];
    }
}

// ---- pack W1 [256][128] fp32 -> W1t [128][256] bf16 (n-major, k contig) ----
__global__ __launch_bounds__(256) void pack_w1t_kernel(const float* __restrict__ W1,
                                                       __hip_bfloat16* __restrict__ W1t) {
    int idx = blockIdx.x * 256 + threadIdx.x;     // 32768 total
    int n = idx >> 8;
    int k = idx & 255;
    W1t[idx] = __float2bfloat16(W1[(size_t)k * F_HID + n]);
}

// ---- GEMM1 (MFMA): h1b[N,128] = bf16( (X*norm_src)bf16 @ W1bf16 ) ----------
__global__ __launch_bounds__(256) void gemm1_mfma_kernel(
    const float* __restrict__ X, const __hip_bfloat16* __restrict__ W1t,
    const float* __restrict__ norm_src, __hip_bfloat16* __restrict__ h1b, int N)
{
    __shared__ __hip_bfloat16 As[64][72];
    __shared__ __hip_bfloat16 Bs[128][72];
    const int t = threadIdx.x;
    const int node0 = blockIdx.x * 64;
    const int lane = t & 63;
    const int w = t >> 6;
    const int l15 = lane & 15;
    const int quad = lane >> 4;

    floatx4 acc[8] = {};

    for (int k0 = 0; k0 < F_IN; k0 += 64) {
        #pragma unroll
        for (int i = 0; i < 4; ++i) {
            int f = t + 256 * i;
            int r = f >> 4;
            int cseg = (f & 15) << 2;
            int node = node0 + r;
            float4 v = make_float4(0.f, 0.f, 0.f, 0.f);
            float ns = 0.f;
            if (node < N) {
                v = *(const float4*)(X + (size_t)node * F_IN + k0 + cseg);
                ns = norm_src[node];
            }
            ushort4 pk;
            pk.x = f2b(v.x * ns);
            pk.y = f2b(v.y * ns);
            pk.z = f2b(v.z * ns);
            pk.w = f2b(v.w * ns);
            *(ushort4*)&As[r][cseg] = pk;
        }
        #pragma unroll
        for (int i = 0; i < 4; ++i) {
            int f = t + 256 * i;
            int n = f >> 3;
            int seg = (f & 7) << 3;
            *(uint4*)&Bs[n][seg] = *(const uint4*)(W1t + (size_t)n * F_IN + k0 + seg);
        }
        __syncthreads();

        const int arow = w * 16 + l15;
        #pragma unroll
        for (int ks = 0; ks < 2; ++ks) {
            bf16x8 a = *(const bf16x8*)&As[arow][ks * 32 + quad * 8];
            #pragma unroll
            for (int nt = 0; nt < 8; ++nt) {
                bf16x8 b = *(const bf16x8*)&Bs[nt * 16 + l15][ks * 32 + quad * 8];
                acc[nt] = __builtin_amdgcn_mfma_f32_16x16x32_bf16(a, b, acc[nt], 0, 0, 0);
            }
        }
        __syncthreads();
    }

    #pragma unroll
    for (int nt = 0; nt < 8; ++nt) {
        #pragma unroll
        for (int r = 0; r < 4; ++r) {
            int node = node0 + w * 16 + quad * 4 + r;
            if (node < N)
                h1b[(size_t)node * F_HID + nt * 16 + l15] = __float2bfloat16(acc[nt][r]);
        }
    }
}

// ---- SpMM1 (CSR, bf16 gather): agg1[n,:] = sum h1b[csr_src,:] --------------
__global__ __launch_bounds__(256) void spmm1_csr_kernel(
    const __hip_bfloat16* __restrict__ h1b, const int* __restrict__ row_off,
    const int* __restrict__ csr_src, float* __restrict__ agg1, int N)
{
    const int t = threadIdx.x;
    const int node = blockIdx.x * 8 + (t >> 5);
    if (node >= N) return;
    const int c = (t & 31) << 2;
    const int start = row_off[node];
    const int end = row_off[node + 1];
    float4 acc = make_float4(0.f, 0.f, 0.f, 0.f);
    for (int j = start; j < end; ++j) {
        int s = csr_src[j];
        ushort4 u = *(const ushort4*)(h1b + (size_t)s * F_HID + c);
        acc.x += b2f(u.x);
        acc.y += b2f(u.y);
        acc.z += b2f(u.z);
        acc.w += b2f(u.w);
    }
    *(float4*)(agg1 + (size_t)node * F_HID + c) = acc;
}

// ---- GEMM2: h2[N,40] = relu(agg1*norm_dst + b1)*norm_src @ W2[128,40] ------
__global__ __launch_bounds__(320) void gemm2_kernel(
    const float* __restrict__ agg1, const float* __restrict__ W2,
    const float* __restrict__ b1, const float* __restrict__ norm_src,
    const float* __restrict__ norm_dst, float* __restrict__ h2, int N)
{
    __shared__ float As[64][132];
    __shared__ float Ws[128][40];
    const int t = threadIdx.x;
    const int node0 = blockIdx.x * 64;

    #pragma unroll
    for (int i = 0; i < 4; ++i) {
        int f = t + 320 * i;
        int r = f / 10;
        int kk = (f % 10) * 4;
        *(float4*)&Ws[r][kk] = *(const float4*)(W2 + (size_t)r * F_CLS + kk);
    }
    for (int f = t; f < 2048; f += 320) {
        int r = f >> 5;
        int kk = (f & 31) << 2;
        int node = node0 + r;
        float4 v = make_float4(0.f, 0.f, 0.f, 0.f);
        if (node < N) {
            float4 a = *(const float4*)(agg1 + (size_t)node * F_HID + kk);
            float nd = norm_dst[node];
            float ns = norm_src[node];
            float4 bb = *(const float4*)(b1 + kk);
            v.x = fmaxf(fmaf(a.x, nd, bb.x), 0.f) * ns;
            v.y = fmaxf(fmaf(a.y, nd, bb.y), 0.f) * ns;
            v.z = fmaxf(fmaf(a.z, nd, bb.z), 0.f) * ns;
            v.w = fmaxf(fmaf(a.w, nd, bb.w), 0.f) * ns;
        }
        *(float4*)&As[r][kk] = v;
    }
    __syncthreads();

    const int col = t % 40;
    const int rowg = t / 40;
    float acc[8] = {};
    #pragma unroll 8
    for (int k = 0; k < F_HID; ++k) {
        float w = Ws[k][col];
        #pragma unroll
        for (int i = 0; i < 8; ++i)
            acc[i] = fmaf(As[rowg * 8 + i][k], w, acc[i]);
    }
    #pragma unroll
    for (int i = 0; i < 8; ++i) {
        int node = node0 + rowg * 8 + i;
        if (node < N) h2[(size_t)node * F_CLS + col] = acc[i];
    }
}

// ---- SpMM2 (CSR) + epilogue: out[n,:] = (sum h2[src,:])*norm_dst[n] + b2 ---
__global__ __launch_bounds__(256) void spmm2_csr_kernel(
    const float* __restrict__ h2, const int* __restrict__ row_off,
    const int* __restrict__ csr_src, const float* __restrict__ norm_dst,
    const float* __restrict__ b2, float* __restrict__ out, int N)
{
    const int t = threadIdx.x;
    const int node = blockIdx.x * 16 + (t >> 4);
    const int lane = t & 15;
    if (node >= N || lane >= 10) return;
    const int c = lane << 2;
    const int start = row_off[node];
    const int end = row_off[node + 1];
    float4 acc = make_float4(0.f, 0.f, 0.f, 0.f);
    for (int j = start; j < end; ++j) {
        int s = csr_src[j];
        float4 v = *(const float4*)(h2 + (size_t)s * F_CLS + c);
        acc.x += v.x; acc.y += v.y; acc.z += v.z; acc.w += v.w;
    }
    float nd = norm_dst[node];
    float4 bb = *(const float4*)(b2 + c);
    float4 r;
    r.x = fmaf(acc.x, nd, bb.x);
    r.y = fmaf(acc.y, nd, bb.y);
    r.z = fmaf(acc.z, nd, bb.z);
    r.w = fmaf(acc.w, nd, bb.w);
    *(float4*)(out + (size_t)node * F_CLS + c) = r;
}

extern "C" void kernel_launch(void* const* d_in, const int* in_sizes, int n_in,
                              void* d_out, int out_size, void* d_ws, size_t ws_size,
                              hipStream_t stream) {
    const float* X   = (const float*)d_in[0];
    const int*   src = (const int*)d_in[1];
    const int*   dst = (const int*)d_in[2];
    const float* W1  = (const float*)d_in[3];
    const float* b1  = (const float*)d_in[4];
    const float* W2  = (const float*)d_in[5];
    const float* b2  = (const float*)d_in[6];
    float* out = (float*)d_out;

    const int N = in_sizes[0] / F_IN;
    const int E = in_sizes[1];
    const int NB = (N + 1023) / 1024;     // scan blocks (<= 256)
    const int NR = (N + RSZ - 1) / RSZ;   // histogram ranges

    // workspace layout — keep every array 16B-aligned
    char* w = (char*)d_ws;
    int*   cnt_dst  = (int*)w;                      w += (size_t)N * 4;
    int*   row_off  = (int*)w;                      w += (size_t)(N + 4) * 4;
    int*   cursor   = (int*)w;                      w += (size_t)N * 4;
    int*   blk_sums = (int*)w;                      w += 256 * 4;
    int*   csr_src  = (int*)w;                      w += (size_t)E * 4;
    float* norm_src = (float*)w;                    w += (size_t)N * 4;
    float* norm_dst = (float*)w;                    w += (size_t)N * 4;
    float* agg1     = (float*)w;                    w += (size_t)N * F_HID * 4;
    float* h2       = (float*)w;                    w += (size_t)N * F_CLS * 4;
    __hip_bfloat16* W1t = (__hip_bfloat16*)w;       w += (size_t)F_HID * F_IN * 2;
    __hip_bfloat16* h1b = (__hip_bfloat16*)w;       w += (size_t)N * F_HID * 2;

    // histogram partials alias agg1+h2 region (dead until spmm1 writes agg1)
    unsigned* partial_s = (unsigned*)agg1;                        // NR*NSL*RSZ
    unsigned* partial_d = partial_s + (size_t)NR * NSL * RSZ;     // NR*NSL*RSZ

    hist_kernel<<<dim3(NR * NSL, 2), 256, 0, stream>>>(src, dst, partial_s, partial_d, E);
    degnorm_kernel<<<(N + 255) / 256, 256, 0, stream>>>(partial_s, partial_d,
                                                        cnt_dst, norm_src, norm_dst, N);

    scan1_kernel<<<NB, 256, 0, stream>>>(cnt_dst, row_off, blk_sums, N);
    scan2_kernel<<<1, 256, 0, stream>>>(blk_sums, NB);
    scan3_kernel<<<NB, 256, 0, stream>>>(row_off, cursor, blk_sums, N, E);
    scatter_kernel<<<(E + 255) / 256, 256, 0, stream>>>(src, dst, cursor, csr_src, E);

    pack_w1t_kernel<<<(F_HID * F_IN) / 256, 256, 0, stream>>>(W1, W1t);

    gemm1_mfma_kernel<<<(N + 63) / 64, 256, 0, stream>>>(X, W1t, norm_src, h1b, N);

    spmm1_csr_kernel<<<(N + 7) / 8, 256, 0, stream>>>(h1b, row_off, csr_src, agg1, N);

    gemm2_kernel<<<(N + 63) / 64, 320, 0, stream>>>(agg1, W2, b1, norm_src, norm_dst, h2, N);

    spmm2_csr_kernel<<<(N + 15) / 16, 256, 0, stream>>>(h2, row_off, csr_src, norm_dst, b2, out, N);
}